// Round 2
// baseline (1716.686 us; speedup 1.0000x reference)
//
#include <hip/hip_runtime.h>

// GMSA restructured:
//   prep:      fold BN into W_in/b_in
//   proj_in:   x[b,60,HW] -> xp bf16 [b][branch][hw][40]  (pixel-major, coalesced)
//   branch x3: window attention from xp; atn -> d_out, y -> ybuf bf16 [b][br][hw][20]
//   proj_out:  ybuf -> out[b,60,HW]
// d_out = [y (8,60,288,288), atn4, atn8, atn12] flat fp32.

constexpr int HW = 288 * 288;
constexpr long long ATN0_OFF = 39813120LL;                 // y elems
constexpr long long ATN1_OFF = ATN0_OFF + 41472LL * 256;   // + atn4
constexpr long long ATN2_OFF = ATN1_OFF + 10368LL * 4096;  // + atn8

// workspace byte offsets (all 16B aligned); total ~239 MB
constexpr size_t YB_OFF = 0;                        // ybuf: 39,813,120 ushort
constexpr size_t WP_OFF = 79626240;                 // Wp: 7200 float
constexpr size_t BP_OFF = WP_OFF + 28800;           // bp: 120 float (pad 512)
constexpr size_t XP_OFF = BP_OFF + 512;             // xp: 79,626,240 ushort

__device__ __forceinline__ float bflo(unsigned u) { return __uint_as_float(u << 16); }
__device__ __forceinline__ float bfhi(unsigned u) { return __uint_as_float(u & 0xffff0000u); }
__device__ __forceinline__ unsigned bfrnd(float f) {             // RNE to bf16 bits
    unsigned u = __float_as_uint(f);
    return (u + 0x7fffu + ((u >> 16) & 1u)) >> 16;
}

// ---------------- prep ----------------
__global__ void prep_kernel(const float* __restrict__ W_in, const float* __restrict__ b_in,
                            const float* __restrict__ gamma, const float* __restrict__ beta,
                            const float* __restrict__ mean, const float* __restrict__ var,
                            float* __restrict__ Wp, float* __restrict__ bp) {
    int o = threadIdx.x;
    if (o < 120) {
        float inv = gamma[o] / sqrtf(var[o] + 1e-5f);
        for (int c = 0; c < 60; ++c) Wp[o * 60 + c] = W_in[o * 60 + c] * inv;
        bp[o] = b_in[o] * inv + beta[o] - mean[o] * inv;
    }
}

// ---------------- proj_in: thread = pixel ----------------
__global__ __launch_bounds__(256, 4) void proj_in_kernel(const float* __restrict__ x,
                                                         const float* __restrict__ Wp,
                                                         const float* __restrict__ bp,
                                                         unsigned short* __restrict__ xp) {
    const long long pixel = (long long)blockIdx.x * 256 + threadIdx.x; // < 8*HW exactly
    const int b  = (int)(pixel / HW);
    const int hw = (int)(pixel % HW);
    float xv[60];
    const float* xb = x + (long long)b * 60 * HW + hw;
    #pragma unroll
    for (int c = 0; c < 60; ++c) xv[c] = xb[(long long)c * HW];
    #pragma unroll
    for (int br = 0; br < 3; ++br) {
        unsigned short* dst = xp + ((long long)(b * 3 + br) * HW + hw) * 40;
        #pragma unroll
        for (int g = 0; g < 5; ++g) {
            float a8[8];
            #pragma unroll
            for (int j = 0; j < 8; ++j) {
                const int oc = br * 40 + g * 8 + j;
                float acc = bp[oc];
                const float* wr = Wp + oc * 60;
                #pragma unroll
                for (int c = 0; c < 60; ++c) acc = fmaf(wr[c], xv[c], acc);
                a8[j] = acc;
            }
            uint4 u;
            u.x = bfrnd(a8[0]) | (bfrnd(a8[1]) << 16);
            u.y = bfrnd(a8[2]) | (bfrnd(a8[3]) << 16);
            u.z = bfrnd(a8[4]) | (bfrnd(a8[5]) << 16);
            u.w = bfrnd(a8[6]) | (bfrnd(a8[7]) << 16);
            *reinterpret_cast<uint4*>(dst + g * 8) = u;
        }
    }
}

// ---------------- branch attention ----------------
template <int WS, int P, int NWIN, int BLOCK, int TPR, int BRANCH, int MINW>
__launch_bounds__(BLOCK, MINW)
__global__ void branch_kernel(const unsigned short* __restrict__ xp,
                              unsigned short* __restrict__ ybuf,
                              float* __restrict__ atn) {
    constexpr int SH = WS / 2;
    constexpr int NWND = 288 / WS;
    constexpr int RSTR = 44;            // row stride (floats), q[0..20) v[20..40)
    constexpr int WSTR = P * RSTR + 8;  // window stride
    constexpr int CPT = P / TPR;

    __shared__ float qv[NWIN * WSTR];

    const int tid = threadIdx.x;
    const int w0 = blockIdx.x * NWIN;

    // ---- stage q|v for NWIN windows: bf16 global -> fp32 LDS ----
    for (int idx = tid; idx < NWIN * P * 5; idx += BLOCK) {
        const int wl  = idx / (P * 5);
        const int rem = idx - wl * (P * 5);
        const int pix = rem / 5;
        const int ch  = rem - pix * 5;
        const int w   = w0 + wl;
        const int b   = w / (NWND * NWND);
        const int r2  = w - b * (NWND * NWND);
        const int wi  = r2 / NWND;
        const int wj  = r2 - wi * NWND;
        const int gh  = (wi * WS + pix / WS + SH) % 288;
        const int gw  = (wj * WS + pix % WS + SH) % 288;
        const long long eoff = ((long long)(b * 3 + BRANCH) * HW + gh * 288 + gw) * 40 + ch * 8;
        const uint4 d = *reinterpret_cast<const uint4*>(xp + eoff);
        float* dst = qv + wl * WSTR + pix * RSTR + ch * 8;
        *reinterpret_cast<float4*>(dst)     = make_float4(bflo(d.x), bfhi(d.x), bflo(d.y), bfhi(d.y));
        *reinterpret_cast<float4*>(dst + 4) = make_float4(bflo(d.z), bfhi(d.z), bflo(d.w), bfhi(d.w));
    }
    __syncthreads();

    // ---- attention ----
    const int widx = tid / (P * TPR);
    const int t    = tid - widx * (P * TPR);
    const int r    = t / TPR;
    const int sub  = t - r * TPR;
    const int w    = w0 + widx;
    const int b    = w / (NWND * NWND);
    const int rem  = w - b * (NWND * NWND);
    const int wi   = rem / NWND;
    const int wj   = rem - wi * NWND;

    const float* base = qv + widx * WSTR;

    float qr[20];
    {
        const float* qrow = base + r * RSTR;
        #pragma unroll
        for (int cc = 0; cc < 5; ++cc) {
            float4 tq = *reinterpret_cast<const float4*>(qrow + cc * 4);
            qr[cc*4+0] = tq.x; qr[cc*4+1] = tq.y; qr[cc*4+2] = tq.z; qr[cc*4+3] = tq.w;
        }
    }

    float s[CPT];
    #pragma unroll
    for (int k = 0; k < CPT; ++k) {
        const float* qj = base + (sub * CPT + k) * RSTR;
        float4 a0 = *reinterpret_cast<const float4*>(qj + 0);
        float4 a1 = *reinterpret_cast<const float4*>(qj + 4);
        float4 a2 = *reinterpret_cast<const float4*>(qj + 8);
        float4 a3 = *reinterpret_cast<const float4*>(qj + 12);
        float4 a4 = *reinterpret_cast<const float4*>(qj + 16);
        float acc = 0.f;
        acc = fmaf(qr[0],  a0.x, acc); acc = fmaf(qr[1],  a0.y, acc);
        acc = fmaf(qr[2],  a0.z, acc); acc = fmaf(qr[3],  a0.w, acc);
        acc = fmaf(qr[4],  a1.x, acc); acc = fmaf(qr[5],  a1.y, acc);
        acc = fmaf(qr[6],  a1.z, acc); acc = fmaf(qr[7],  a1.w, acc);
        acc = fmaf(qr[8],  a2.x, acc); acc = fmaf(qr[9],  a2.y, acc);
        acc = fmaf(qr[10], a2.z, acc); acc = fmaf(qr[11], a2.w, acc);
        acc = fmaf(qr[12], a3.x, acc); acc = fmaf(qr[13], a3.y, acc);
        acc = fmaf(qr[14], a3.z, acc); acc = fmaf(qr[15], a3.w, acc);
        acc = fmaf(qr[16], a4.x, acc); acc = fmaf(qr[17], a4.y, acc);
        acc = fmaf(qr[18], a4.z, acc); acc = fmaf(qr[19], a4.w, acc);
        s[k] = acc;
    }

    float m = s[0];
    #pragma unroll
    for (int k = 1; k < CPT; ++k) m = fmaxf(m, s[k]);
    if constexpr (TPR >= 2) m = fmaxf(m, __shfl_xor(m, 1, TPR));
    if constexpr (TPR >= 4) m = fmaxf(m, __shfl_xor(m, 2, TPR));
    float sum = 0.f;
    #pragma unroll
    for (int k = 0; k < CPT; ++k) { s[k] = __expf(s[k] - m); sum += s[k]; }
    if constexpr (TPR >= 2) sum += __shfl_xor(sum, 1, TPR);
    if constexpr (TPR >= 4) sum += __shfl_xor(sum, 2, TPR);
    const float inv = 1.0f / sum;
    #pragma unroll
    for (int k = 0; k < CPT; ++k) s[k] *= inv;

    // atn row chunk (contiguous, coalesced)
    float* arow = atn + ((long long)w * P + r) * P + sub * CPT;
    #pragma unroll
    for (int k = 0; k < CPT; k += 4)
        *reinterpret_cast<float4*>(arow + k) = make_float4(s[k], s[k+1], s[k+2], s[k+3]);

    // y = atn @ v
    float acc[20];
    #pragma unroll
    for (int c = 0; c < 20; ++c) acc[c] = 0.f;
    #pragma unroll
    for (int k = 0; k < CPT; ++k) {
        const float* vj = base + (sub * CPT + k) * RSTR + 20;
        const float a = s[k];
        float4 b0 = *reinterpret_cast<const float4*>(vj + 0);
        float4 b1 = *reinterpret_cast<const float4*>(vj + 4);
        float4 b2 = *reinterpret_cast<const float4*>(vj + 8);
        float4 b3 = *reinterpret_cast<const float4*>(vj + 12);
        float4 b4 = *reinterpret_cast<const float4*>(vj + 16);
        acc[0]  = fmaf(a, b0.x, acc[0]);  acc[1]  = fmaf(a, b0.y, acc[1]);
        acc[2]  = fmaf(a, b0.z, acc[2]);  acc[3]  = fmaf(a, b0.w, acc[3]);
        acc[4]  = fmaf(a, b1.x, acc[4]);  acc[5]  = fmaf(a, b1.y, acc[5]);
        acc[6]  = fmaf(a, b1.z, acc[6]);  acc[7]  = fmaf(a, b1.w, acc[7]);
        acc[8]  = fmaf(a, b2.x, acc[8]);  acc[9]  = fmaf(a, b2.y, acc[9]);
        acc[10] = fmaf(a, b2.z, acc[10]); acc[11] = fmaf(a, b2.w, acc[11]);
        acc[12] = fmaf(a, b3.x, acc[12]); acc[13] = fmaf(a, b3.y, acc[13]);
        acc[14] = fmaf(a, b3.z, acc[14]); acc[15] = fmaf(a, b3.w, acc[15]);
        acc[16] = fmaf(a, b4.x, acc[16]); acc[17] = fmaf(a, b4.y, acc[17]);
        acc[18] = fmaf(a, b4.z, acc[18]); acc[19] = fmaf(a, b4.w, acc[19]);
    }
    if constexpr (TPR >= 2) {
        #pragma unroll
        for (int c = 0; c < 20; ++c) acc[c] += __shfl_xor(acc[c], 1, TPR);
    }
    if constexpr (TPR >= 4) {
        #pragma unroll
        for (int c = 0; c < 20; ++c) acc[c] += __shfl_xor(acc[c], 2, TPR);
    }

    if (TPR == 1 || sub == 0) {
        const int oh = (wi * WS + r / WS + SH) % 288;
        const int ow = (wj * WS + r % WS + SH) % 288;
        unsigned short* yb = ybuf + ((long long)(b * 3 + BRANCH) * HW + oh * 288 + ow) * 20;
        #pragma unroll
        for (int k = 0; k < 5; ++k) {
            uint2 u;
            u.x = bfrnd(acc[k*4+0]) | (bfrnd(acc[k*4+1]) << 16);
            u.y = bfrnd(acc[k*4+2]) | (bfrnd(acc[k*4+3]) << 16);
            *reinterpret_cast<uint2*>(yb + k * 4) = u;
        }
    }
}

// ---------------- proj_out: thread = pixel ----------------
__global__ __launch_bounds__(256, 4) void proj_out_kernel(const unsigned short* __restrict__ ybuf,
                                                          const float* __restrict__ Wout,
                                                          const float* __restrict__ bout,
                                                          float* __restrict__ out) {
    const long long pixel = (long long)blockIdx.x * 256 + threadIdx.x;
    const int b  = (int)(pixel / HW);
    const int hw = (int)(pixel % HW);
    float yv[60];
    #pragma unroll
    for (int br = 0; br < 3; ++br) {
        const unsigned short* yb = ybuf + ((long long)(b * 3 + br) * HW + hw) * 20;
        #pragma unroll
        for (int k = 0; k < 5; ++k) {
            uint2 u = *reinterpret_cast<const uint2*>(yb + k * 4);
            yv[br*20 + k*4 + 0] = bflo(u.x);
            yv[br*20 + k*4 + 1] = bfhi(u.x);
            yv[br*20 + k*4 + 2] = bflo(u.y);
            yv[br*20 + k*4 + 3] = bfhi(u.y);
        }
    }
    #pragma unroll 4
    for (int o = 0; o < 60; ++o) {
        float acc = bout[o];
        const float* wr = Wout + o * 60;
        #pragma unroll
        for (int c = 0; c < 60; ++c) acc = fmaf(wr[c], yv[c], acc);
        out[((long long)b * 60 + o) * HW + hw] = acc;
    }
}

extern "C" void kernel_launch(void* const* d_in, const int* in_sizes, int n_in,
                              void* d_out, int out_size, void* d_ws, size_t ws_size,
                              hipStream_t stream) {
    const float* x     = (const float*)d_in[0];
    const float* W_in  = (const float*)d_in[1];
    const float* b_in  = (const float*)d_in[2];
    const float* gamma = (const float*)d_in[3];
    const float* beta  = (const float*)d_in[4];
    const float* mean  = (const float*)d_in[5];
    const float* var   = (const float*)d_in[6];
    const float* Wout  = (const float*)d_in[7];
    const float* bout  = (const float*)d_in[8];
    float* out = (float*)d_out;

    char* wsb = (char*)d_ws;
    unsigned short* ybuf = (unsigned short*)(wsb + YB_OFF);
    float*          Wp   = (float*)(wsb + WP_OFF);
    float*          bp   = (float*)(wsb + BP_OFF);
    unsigned short* xp   = (unsigned short*)(wsb + XP_OFF);

    prep_kernel<<<1, 128, 0, stream>>>(W_in, b_in, gamma, beta, mean, var, Wp, bp);
    proj_in_kernel<<<2592, 256, 0, stream>>>(x, Wp, bp, xp);

    branch_kernel<4, 16, 16, 256, 1, 0, 4><<<2592, 256, 0, stream>>>(xp, ybuf, out + ATN0_OFF);
    branch_kernel<8, 64, 2, 256, 2, 1, 4><<<5184, 256, 0, stream>>>(xp, ybuf, out + ATN1_OFF);
    branch_kernel<12, 144, 1, 576, 4, 2, 2><<<4608, 576, 0, stream>>>(xp, ybuf, out + ATN2_OFF);

    proj_out_kernel<<<2592, 256, 0, stream>>>(ybuf, Wout, bout, out);
}

// Round 3
// 907.340 us; speedup vs baseline: 1.8920x; 1.8920x over previous
//
#include <hip/hip_runtime.h>

// GMSA: prep -> proj_in (x -> xp bf16 pixel-major) -> 3x window attention -> proj_out
// All hot global streams are dense per-wave bursts (LDS-staged).
// d_out = [y (8,60,288,288), atn4, atn8, atn12] flat fp32.

constexpr int HW = 288 * 288;
constexpr long long ATN0_OFF = 39813120LL;
constexpr long long ATN1_OFF = ATN0_OFF + 41472LL * 256;
constexpr long long ATN2_OFF = ATN1_OFF + 10368LL * 4096;

// workspace byte offsets
constexpr size_t YB_OFF = 0;                        // ybuf: 39,813,120 ushort (pixel-major [b][br][hw][20])
constexpr size_t WP_OFF = 79626240;                 // Wp: 7200 float
constexpr size_t BP_OFF = WP_OFF + 28800;           // bp: 120 float (+pad)
constexpr size_t XP_OFF = BP_OFF + 512;             // xp: 79,626,240 ushort ([b][br][hw][40])

__device__ __forceinline__ float bflo(unsigned u) { return __uint_as_float(u << 16); }
__device__ __forceinline__ float bfhi(unsigned u) { return __uint_as_float(u & 0xffff0000u); }
__device__ __forceinline__ unsigned bfrnd(float f) {
    unsigned u = __float_as_uint(f);
    return (u + 0x7fffu + ((u >> 16) & 1u)) >> 16;
}
__device__ __forceinline__ unsigned bfpack(float a, float b) { return bfrnd(a) | (bfrnd(b) << 16); }

// ---------------- prep ----------------
__global__ void prep_kernel(const float* __restrict__ W_in, const float* __restrict__ b_in,
                            const float* __restrict__ gamma, const float* __restrict__ beta,
                            const float* __restrict__ mean, const float* __restrict__ var,
                            float* __restrict__ Wp, float* __restrict__ bp) {
    int o = threadIdx.x;
    if (o < 120) {
        float inv = gamma[o] / sqrtf(var[o] + 1e-5f);
        for (int c = 0; c < 60; ++c) Wp[o * 60 + c] = W_in[o * 60 + c] * inv;
        bp[o] = b_in[o] * inv + beta[o] - mean[o] * inv;
    }
}

// ---------------- proj_in ----------------
// block = 256 consecutive pixels of one b. Dense uint4 burst stores via LDS.
__global__ __launch_bounds__(256, 4) void proj_in_kernel(const float* __restrict__ x,
                                                         const float* __restrict__ Wp,
                                                         const float* __restrict__ bp,
                                                         unsigned short* __restrict__ xp) {
    __shared__ unsigned pk[256 * 21];   // padded stride 21 u32
    const int tid = threadIdx.x;
    const long long pixel0 = (long long)blockIdx.x * 256;
    const int b   = (int)(pixel0 / HW);
    const int hw0 = (int)(pixel0 % HW);          // multiple of 256

    float xv[60];
    const float* xb = x + (long long)b * 60 * HW + hw0 + tid;
    #pragma unroll
    for (int c = 0; c < 60; ++c) xv[c] = xb[(long long)c * HW];

    for (int br = 0; br < 3; ++br) {
        #pragma unroll
        for (int g = 0; g < 5; ++g) {
            float a8[8];
            #pragma unroll
            for (int j = 0; j < 8; ++j) {
                const int oc = br * 40 + g * 8 + j;
                float acc = bp[oc];
                const float* wr = Wp + oc * 60;
                #pragma unroll
                for (int c = 0; c < 60; ++c) acc = fmaf(wr[c], xv[c], acc);
                a8[j] = acc;
            }
            pk[tid * 21 + g * 4 + 0] = bfpack(a8[0], a8[1]);
            pk[tid * 21 + g * 4 + 1] = bfpack(a8[2], a8[3]);
            pk[tid * 21 + g * 4 + 2] = bfpack(a8[4], a8[5]);
            pk[tid * 21 + g * 4 + 3] = bfpack(a8[6], a8[7]);
        }
        __syncthreads();
        // 256 pixels * 20 u32 = 1280 uint4, fully contiguous
        uint4* dst = reinterpret_cast<uint4*>(xp + ((long long)(b * 3 + br) * HW + hw0) * 40);
        #pragma unroll
        for (int it = 0; it < 5; ++it) {
            const int i = it * 256 + tid;
            const int p = i / 5, c = i % 5;
            const unsigned* s = pk + p * 21 + c * 4;
            dst[i] = make_uint4(s[0], s[1], s[2], s[3]);
        }
        __syncthreads();
    }
}

// ---------------- branch attention ----------------
template <int WS, int P, int NWIN, int BLOCK, int TPR, int BRANCH, int MINW>
__launch_bounds__(BLOCK, MINW)
__global__ void branch_kernel(const unsigned short* __restrict__ xp,
                              unsigned short* __restrict__ ybuf,
                              float* __restrict__ atn) {
    constexpr int SH = WS / 2;
    constexpr int NWND = 288 / WS;
    constexpr int RSTR = 44;            // row stride (floats): q[0..20) v[20..40)
    constexpr int WSTR = P * RSTR + 8;
    constexpr int CPT = P / TPR;

    __shared__ float qv[NWIN * WSTR];
    unsigned* ys = reinterpret_cast<unsigned*>(qv);  // aliased after attention (needs NWIN*P*10 u32 <= NWIN*WSTR)

    const int tid = threadIdx.x;
    const int w0 = blockIdx.x * NWIN;

    // ---- stage q|v: bf16 global -> fp32 LDS ----
    for (int idx = tid; idx < NWIN * P * 5; idx += BLOCK) {
        const int wl  = idx / (P * 5);
        const int rem = idx - wl * (P * 5);
        const int pix = rem / 5;
        const int ch  = rem - pix * 5;
        const int w   = w0 + wl;
        const int b   = w / (NWND * NWND);
        const int r2  = w - b * (NWND * NWND);
        const int wi  = r2 / NWND;
        const int wj  = r2 - wi * NWND;
        const int gh  = (wi * WS + pix / WS + SH) % 288;
        const int gw  = (wj * WS + pix % WS + SH) % 288;
        const long long eoff = ((long long)(b * 3 + BRANCH) * HW + gh * 288 + gw) * 40 + ch * 8;
        const uint4 d = *reinterpret_cast<const uint4*>(xp + eoff);
        float* dst = qv + wl * WSTR + pix * RSTR + ch * 8;
        *reinterpret_cast<float4*>(dst)     = make_float4(bflo(d.x), bfhi(d.x), bflo(d.y), bfhi(d.y));
        *reinterpret_cast<float4*>(dst + 4) = make_float4(bflo(d.z), bfhi(d.z), bflo(d.w), bfhi(d.w));
    }
    __syncthreads();

    // ---- attention ----
    const int widx = tid / (P * TPR);
    const int t    = tid - widx * (P * TPR);
    const int r    = t / TPR;
    const int sub  = t - r * TPR;
    const int w    = w0 + widx;

    const float* base = qv + widx * WSTR;

    float qr[20];
    {
        const float* qrow = base + r * RSTR;
        #pragma unroll
        for (int cc = 0; cc < 5; ++cc) {
            float4 tq = *reinterpret_cast<const float4*>(qrow + cc * 4);
            qr[cc*4+0] = tq.x; qr[cc*4+1] = tq.y; qr[cc*4+2] = tq.z; qr[cc*4+3] = tq.w;
        }
    }

    float s[CPT];
    #pragma unroll
    for (int k = 0; k < CPT; ++k) {
        const float* qj = base + (sub * CPT + k) * RSTR;
        float4 a0 = *reinterpret_cast<const float4*>(qj + 0);
        float4 a1 = *reinterpret_cast<const float4*>(qj + 4);
        float4 a2 = *reinterpret_cast<const float4*>(qj + 8);
        float4 a3 = *reinterpret_cast<const float4*>(qj + 12);
        float4 a4 = *reinterpret_cast<const float4*>(qj + 16);
        float acc = 0.f;
        acc = fmaf(qr[0],  a0.x, acc); acc = fmaf(qr[1],  a0.y, acc);
        acc = fmaf(qr[2],  a0.z, acc); acc = fmaf(qr[3],  a0.w, acc);
        acc = fmaf(qr[4],  a1.x, acc); acc = fmaf(qr[5],  a1.y, acc);
        acc = fmaf(qr[6],  a1.z, acc); acc = fmaf(qr[7],  a1.w, acc);
        acc = fmaf(qr[8],  a2.x, acc); acc = fmaf(qr[9],  a2.y, acc);
        acc = fmaf(qr[10], a2.z, acc); acc = fmaf(qr[11], a2.w, acc);
        acc = fmaf(qr[12], a3.x, acc); acc = fmaf(qr[13], a3.y, acc);
        acc = fmaf(qr[14], a3.z, acc); acc = fmaf(qr[15], a3.w, acc);
        acc = fmaf(qr[16], a4.x, acc); acc = fmaf(qr[17], a4.y, acc);
        acc = fmaf(qr[18], a4.z, acc); acc = fmaf(qr[19], a4.w, acc);
        s[k] = acc;
    }

    float m = s[0];
    #pragma unroll
    for (int k = 1; k < CPT; ++k) m = fmaxf(m, s[k]);
    if constexpr (TPR >= 2) m = fmaxf(m, __shfl_xor(m, 1, TPR));
    if constexpr (TPR >= 4) m = fmaxf(m, __shfl_xor(m, 2, TPR));
    float sum = 0.f;
    #pragma unroll
    for (int k = 0; k < CPT; ++k) { s[k] = __expf(s[k] - m); sum += s[k]; }
    if constexpr (TPR >= 2) sum += __shfl_xor(sum, 1, TPR);
    if constexpr (TPR >= 4) sum += __shfl_xor(sum, 2, TPR);
    const float inv = 1.0f / sum;
    #pragma unroll
    for (int k = 0; k < CPT; ++k) s[k] *= inv;

    // atn writes: contiguous float4 per thread, dense across block
    float* arow = atn + ((long long)w * P + r) * P + sub * CPT;
    #pragma unroll
    for (int k = 0; k < CPT; k += 4)
        *reinterpret_cast<float4*>(arow + k) = make_float4(s[k], s[k+1], s[k+2], s[k+3]);

    // y = atn @ v
    float acc[20];
    #pragma unroll
    for (int c = 0; c < 20; ++c) acc[c] = 0.f;
    #pragma unroll
    for (int k = 0; k < CPT; ++k) {
        const float* vj = base + (sub * CPT + k) * RSTR + 20;
        const float a = s[k];
        float4 b0 = *reinterpret_cast<const float4*>(vj + 0);
        float4 b1 = *reinterpret_cast<const float4*>(vj + 4);
        float4 b2 = *reinterpret_cast<const float4*>(vj + 8);
        float4 b3 = *reinterpret_cast<const float4*>(vj + 12);
        float4 b4 = *reinterpret_cast<const float4*>(vj + 16);
        acc[0]  = fmaf(a, b0.x, acc[0]);  acc[1]  = fmaf(a, b0.y, acc[1]);
        acc[2]  = fmaf(a, b0.z, acc[2]);  acc[3]  = fmaf(a, b0.w, acc[3]);
        acc[4]  = fmaf(a, b1.x, acc[4]);  acc[5]  = fmaf(a, b1.y, acc[5]);
        acc[6]  = fmaf(a, b1.z, acc[6]);  acc[7]  = fmaf(a, b1.w, acc[7]);
        acc[8]  = fmaf(a, b2.x, acc[8]);  acc[9]  = fmaf(a, b2.y, acc[9]);
        acc[10] = fmaf(a, b2.z, acc[10]); acc[11] = fmaf(a, b2.w, acc[11]);
        acc[12] = fmaf(a, b3.x, acc[12]); acc[13] = fmaf(a, b3.y, acc[13]);
        acc[14] = fmaf(a, b3.z, acc[14]); acc[15] = fmaf(a, b3.w, acc[15]);
        acc[16] = fmaf(a, b4.x, acc[16]); acc[17] = fmaf(a, b4.y, acc[17]);
        acc[18] = fmaf(a, b4.z, acc[18]); acc[19] = fmaf(a, b4.w, acc[19]);
    }
    if constexpr (TPR >= 2) {
        #pragma unroll
        for (int c = 0; c < 20; ++c) acc[c] += __shfl_xor(acc[c], 1, TPR);
    }
    if constexpr (TPR >= 4) {
        #pragma unroll
        for (int c = 0; c < 20; ++c) acc[c] += __shfl_xor(acc[c], 2, TPR);
    }

    // ---- stage y (bf16 packed) into aliased LDS, then dense cooperative write ----
    __syncthreads();   // all qv reads complete
    if (TPR == 1 || sub == 0) {
        unsigned* yrow = ys + (widx * P + r) * 10;
        #pragma unroll
        for (int k = 0; k < 10; ++k) yrow[k] = bfpack(acc[2*k], acc[2*k+1]);
    }
    __syncthreads();

    // uint2 chunks: 5 per pixel (40B), contiguous within each window row; wrap-safe
    for (int i = tid; i < NWIN * P * 5; i += BLOCK) {
        const int wl   = i / (P * 5);
        const int rem  = i - wl * (P * 5);
        const int pixr = rem / 5;
        const int c    = rem - pixr * 5;
        const int w2   = w0 + wl;
        const int b2   = w2 / (NWND * NWND);
        const int r2   = w2 - b2 * (NWND * NWND);
        const int wi2  = r2 / NWND;
        const int wj2  = r2 - wi2 * NWND;
        const int oh   = (wi2 * WS + pixr / WS + SH) % 288;
        const int ow   = (wj2 * WS + pixr % WS + SH) % 288;
        unsigned* dst = reinterpret_cast<unsigned*>(ybuf) +
                        ((long long)(b2 * 3 + BRANCH) * HW + oh * 288 + ow) * 10 + c * 2;
        const unsigned* s2 = ys + (wl * P + pixr) * 10 + c * 2;
        *reinterpret_cast<uint2*>(dst) = make_uint2(s2[0], s2[1]);
    }
}

// ---------------- proj_out ----------------
// block = 256 consecutive pixels of one b. Dense loads + dense 1KB-segment stores via LDS.
__global__ __launch_bounds__(256, 3) void proj_out_kernel(const unsigned short* __restrict__ ybuf,
                                                          const float* __restrict__ Wout,
                                                          const float* __restrict__ bout,
                                                          float* __restrict__ out) {
    __shared__ unsigned ystage[3][2560 + 8];   // 256 pix * 10 u32 per branch
    __shared__ float ostage[15][260];
    const int tid = threadIdx.x;
    const long long pixel0 = (long long)blockIdx.x * 256;
    const int b   = (int)(pixel0 / HW);
    const int hw0 = (int)(pixel0 % HW);

    // dense cooperative load: 3 branches * 640 uint4
    for (int i = tid; i < 3 * 640; i += 256) {
        const int br = i / 640, j = i - br * 640;
        const uint4 d = reinterpret_cast<const uint4*>(
            ybuf + ((long long)(b * 3 + br) * HW + hw0) * 20)[j];
        unsigned* dstl = &ystage[br][j * 4];
        dstl[0] = d.x; dstl[1] = d.y; dstl[2] = d.z; dstl[3] = d.w;
    }
    __syncthreads();

    float yv[60];
    #pragma unroll
    for (int br = 0; br < 3; ++br) {
        #pragma unroll
        for (int k = 0; k < 10; ++k) {
            const unsigned u = ystage[br][tid * 10 + k];
            yv[br * 20 + 2*k]     = bflo(u);
            yv[br * 20 + 2*k + 1] = bfhi(u);
        }
    }

    for (int c0 = 0; c0 < 60; c0 += 15) {
        #pragma unroll
        for (int oo = 0; oo < 15; ++oo) {
            const int o = c0 + oo;
            float acc = bout[o];
            const float* wr = Wout + o * 60;
            #pragma unroll
            for (int c = 0; c < 60; ++c) acc = fmaf(wr[c], yv[c], acc);
            ostage[oo][tid] = acc;
        }
        __syncthreads();
        // 15 segments * 64 uint4, each segment = 1KB dense
        for (int i = tid; i < 15 * 64; i += 256) {
            const int seg = i / 64, j = i - seg * 64;
            const float* sl = &ostage[seg][j * 4];
            float4 vq = make_float4(sl[0], sl[1], sl[2], sl[3]);
            *reinterpret_cast<float4*>(out + ((long long)b * 60 + c0 + seg) * HW + hw0 + j * 4) = vq;
        }
        __syncthreads();
    }
}

extern "C" void kernel_launch(void* const* d_in, const int* in_sizes, int n_in,
                              void* d_out, int out_size, void* d_ws, size_t ws_size,
                              hipStream_t stream) {
    const float* x     = (const float*)d_in[0];
    const float* W_in  = (const float*)d_in[1];
    const float* b_in  = (const float*)d_in[2];
    const float* gamma = (const float*)d_in[3];
    const float* beta  = (const float*)d_in[4];
    const float* mean  = (const float*)d_in[5];
    const float* var   = (const float*)d_in[6];
    const float* Wout  = (const float*)d_in[7];
    const float* bout  = (const float*)d_in[8];
    float* out = (float*)d_out;

    char* wsb = (char*)d_ws;
    unsigned short* ybuf = (unsigned short*)(wsb + YB_OFF);
    float*          Wp   = (float*)(wsb + WP_OFF);
    float*          bp   = (float*)(wsb + BP_OFF);
    unsigned short* xp   = (unsigned short*)(wsb + XP_OFF);

    prep_kernel<<<1, 128, 0, stream>>>(W_in, b_in, gamma, beta, mean, var, Wp, bp);
    proj_in_kernel<<<2592, 256, 0, stream>>>(x, Wp, bp, xp);

    branch_kernel<4, 16, 16, 256, 1, 0, 2><<<2592, 256, 0, stream>>>(xp, ybuf, out + ATN0_OFF);
    branch_kernel<8, 64, 2, 256, 2, 1, 2><<<5184, 256, 0, stream>>>(xp, ybuf, out + ATN1_OFF);
    branch_kernel<12, 144, 1, 576, 4, 2, 2><<<4608, 576, 0, stream>>>(xp, ybuf, out + ATN2_OFF);

    proj_out_kernel<<<2592, 256, 0, stream>>>(ybuf, Wout, bout, out);
}

// Round 5
// 679.141 us; speedup vs baseline: 2.5277x; 1.3360x over previous
//
#include <hip/hip_runtime.h>

// GMSA: prep -> proj_in (x -> xp bf16 pixel-major) -> 3x MFMA window attention -> proj_out
// d_out = [y (8,60,288,288), atn4, atn8, atn12] flat fp32.
//
// Attention via MFMA, exploiting S = Q.Q^T symmetry:
//  - one bf16x8 fragment per 16-row tile serves as BOTH A and B operand of
//    mfma_f32_16x16x32_bf16 (k-mapping mistakes cancel: same bijection both sides).
//  - C-layout (col=lane&15,row=4g+reg; m89-verified) read symmetrically:
//    softmax row = 16j+(lane&15), col = 16i+4g+reg -> reduce = in-lane + shfl_xor 16,32.
//  - post-softmax P per lane == A-frag of mfma_f32_16x16x16_bf16 exactly -> PV shuffle-free.
//
// R5 fix vs R4: ws=8 grid was 1296 (half the 10368 windows). Now 2592.

constexpr int HW = 288 * 288;
constexpr long long ATN0_OFF = 39813120LL;
constexpr long long ATN1_OFF = ATN0_OFF + 41472LL * 256;
constexpr long long ATN2_OFF = ATN1_OFF + 10368LL * 4096;

constexpr size_t YB_OFF = 0;
constexpr size_t WP_OFF = 79626240;
constexpr size_t BP_OFF = WP_OFF + 28800;
constexpr size_t XP_OFF = BP_OFF + 512;

typedef __attribute__((ext_vector_type(8))) short  bf16x8;
typedef __attribute__((ext_vector_type(4))) short  bf16x4;
typedef __attribute__((ext_vector_type(4))) float  f32x4;

__device__ __forceinline__ float bflo(unsigned u) { return __uint_as_float(u << 16); }
__device__ __forceinline__ float bfhi(unsigned u) { return __uint_as_float(u & 0xffff0000u); }
__device__ __forceinline__ unsigned bfrnd(float f) {
    unsigned u = __float_as_uint(f);
    return (u + 0x7fffu + ((u >> 16) & 1u)) >> 16;
}
__device__ __forceinline__ unsigned bfpack(float a, float b) { return bfrnd(a) | (bfrnd(b) << 16); }

#if defined(__has_builtin)
#if __has_builtin(__builtin_amdgcn_mfma_f32_16x16x16bf16_1k)
#define HAVE_MFMA16 1
#endif
#endif

__device__ __forceinline__ f32x4 mfma16(bf16x4 a, bf16x4 b, f32x4 c) {
#ifdef HAVE_MFMA16
    return __builtin_amdgcn_mfma_f32_16x16x16bf16_1k(a, b, c, 0, 0, 0);
#else
    f32x4 d;
    asm("v_mfma_f32_16x16x16_bf16 %0, %1, %2, %3" : "=v"(d) : "v"(a), "v"(b), "v"(c));
    return d;
#endif
}

// ---------------- prep ----------------
__global__ void prep_kernel(const float* __restrict__ W_in, const float* __restrict__ b_in,
                            const float* __restrict__ gamma, const float* __restrict__ beta,
                            const float* __restrict__ mean, const float* __restrict__ var,
                            float* __restrict__ Wp, float* __restrict__ bp) {
    int o = threadIdx.x;
    if (o < 120) {
        float inv = gamma[o] / sqrtf(var[o] + 1e-5f);
        for (int c = 0; c < 60; ++c) Wp[o * 60 + c] = W_in[o * 60 + c] * inv;
        bp[o] = b_in[o] * inv + beta[o] - mean[o] * inv;
    }
}

// ---------------- proj_in ----------------
__global__ __launch_bounds__(256, 4) void proj_in_kernel(const float* __restrict__ x,
                                                         const float* __restrict__ Wp,
                                                         const float* __restrict__ bp,
                                                         unsigned short* __restrict__ xp) {
    __shared__ unsigned pk[256 * 21];
    const int tid = threadIdx.x;
    const long long pixel0 = (long long)blockIdx.x * 256;
    const int b   = (int)(pixel0 / HW);
    const int hw0 = (int)(pixel0 % HW);

    float xv[60];
    const float* xb = x + (long long)b * 60 * HW + hw0 + tid;
    #pragma unroll
    for (int c = 0; c < 60; ++c) xv[c] = xb[(long long)c * HW];

    for (int br = 0; br < 3; ++br) {
        #pragma unroll
        for (int g = 0; g < 5; ++g) {
            float a8[8];
            #pragma unroll
            for (int j = 0; j < 8; ++j) {
                const int oc = br * 40 + g * 8 + j;
                float acc = bp[oc];
                const float* wr = Wp + oc * 60;
                #pragma unroll
                for (int c = 0; c < 60; ++c) acc = fmaf(wr[c], xv[c], acc);
                a8[j] = acc;
            }
            pk[tid * 21 + g * 4 + 0] = bfpack(a8[0], a8[1]);
            pk[tid * 21 + g * 4 + 1] = bfpack(a8[2], a8[3]);
            pk[tid * 21 + g * 4 + 2] = bfpack(a8[4], a8[5]);
            pk[tid * 21 + g * 4 + 3] = bfpack(a8[6], a8[7]);
        }
        __syncthreads();
        uint4* dst = reinterpret_cast<uint4*>(xp + ((long long)(b * 3 + br) * HW + hw0) * 40);
        #pragma unroll
        for (int it = 0; it < 5; ++it) {
            const int i = it * 256 + tid;
            const int p = i / 5, c = i % 5;
            const unsigned* s = pk + p * 21 + c * 4;
            dst[i] = make_uint4(s[0], s[1], s[2], s[3]);
        }
        __syncthreads();
    }
}

// ---------------- MFMA branch attention ----------------
template <int WS, int NWIN, int BLOCK, int WPW, int BRANCH, int MINW>
__launch_bounds__(BLOCK, MINW)
__global__ void branch_kernel(const unsigned short* __restrict__ xp,
                              unsigned short* __restrict__ ybuf,
                              float* __restrict__ atn) {
    constexpr int P    = WS * WS;
    constexpr int RT   = P / 16;
    constexpr int SH   = WS / 2;
    constexpr int NWND = 288 / WS;
    constexpr int RSTR = 56;
    constexpr int WAVES = BLOCK / 64;
    constexpr int WINS_PER_WAVE = (NWIN * WPW) / WAVES;

    __shared__ __align__(16) unsigned short qv[NWIN * P * RSTR];
    __shared__ __align__(16) unsigned short ys[NWIN * P * 20];

    const int tid = threadIdx.x;
    const int w0 = blockIdx.x * NWIN;

    for (int idx = tid; idx < NWIN * P * 5; idx += BLOCK) {
        const int wl  = idx / (P * 5);
        const int rem = idx - wl * (P * 5);
        const int pix = rem / 5;
        const int ck  = rem - pix * 5;
        const int w   = w0 + wl;
        const int b   = w / (NWND * NWND);
        const int r2  = w - b * (NWND * NWND);
        const int wi  = r2 / NWND;
        const int wj  = r2 - wi * NWND;
        const int gh  = (wi * WS + pix / WS + SH) % 288;
        const int gw  = (wj * WS + pix % WS + SH) % 288;
        const uint4 d = *reinterpret_cast<const uint4*>(
            xp + ((long long)(b * 3 + BRANCH) * HW + gh * 288 + gw) * 40 + ck * 8);
        *reinterpret_cast<uint4*>(&qv[(wl * P + pix) * RSTR + ck * 8]) = d;
    }
    __syncthreads();

    const int wave = tid >> 6;
    const int lane = tid & 63;
    const int lo   = lane & 15;
    const int g    = lane >> 4;

    for (int wk = 0; wk < WINS_PER_WAVE; ++wk) {
        const int wl   = (WPW == 1) ? (wave * WINS_PER_WAVE + wk) : (wave >> 1);
        const int half = (WPW == 1) ? 0 : (wave & 1);
        const int w    = w0 + wl;
        const unsigned short* wbase = qv + wl * P * RSTR;

        bf16x8 F[RT];
        #pragma unroll
        for (int t = 0; t < RT; ++t) {
            uint4 u = *reinterpret_cast<const uint4*>(&wbase[(16 * t + lo) * RSTR + g * 8]);
            if (g == 2) { u.z = 0; u.w = 0; }
            if (g == 3) { u.x = 0; u.y = 0; u.z = 0; u.w = 0; }
            F[t] = *reinterpret_cast<bf16x8*>(&u);
        }

        bf16x4 VB[RT][2];
        #pragma unroll
        for (int i = 0; i < RT; ++i) {
            #pragma unroll
            for (int ct = 0; ct < 2; ++ct) {
                const int c = ct * 16 + lo;
                bf16x4 vv;
                #pragma unroll
                for (int jj = 0; jj < 4; ++jj) {
                    const int row = 16 * i + 4 * g + jj;
                    vv[jj] = (c < 20) ? (short)wbase[row * RSTR + 20 + c] : (short)0;
                }
                VB[i][ct] = vv;
            }
        }

        const int jstart = (WPW == 1) ? 0 : (half * ((RT + 1) / 2));
        const int jend   = (WPW == 1) ? RT : ((half == 0) ? ((RT + 1) / 2) : RT);
        for (int j = jstart; j < jend; ++j) {
            f32x4 S[RT];
            #pragma unroll
            for (int i = 0; i < RT; ++i) {
                f32x4 z = {0.f, 0.f, 0.f, 0.f};
                S[i] = __builtin_amdgcn_mfma_f32_16x16x32_bf16(F[i], F[j], z, 0, 0, 0);
            }

            float m = S[0][0];
            #pragma unroll
            for (int i = 0; i < RT; ++i) {
                #pragma unroll
                for (int r = 0; r < 4; ++r) m = fmaxf(m, S[i][r]);
            }
            m = fmaxf(m, __shfl_xor(m, 16));
            m = fmaxf(m, __shfl_xor(m, 32));
            float sum = 0.f;
            #pragma unroll
            for (int i = 0; i < RT; ++i) {
                #pragma unroll
                for (int r = 0; r < 4; ++r) { float e = __expf(S[i][r] - m); S[i][r] = e; sum += e; }
            }
            sum += __shfl_xor(sum, 16);
            sum += __shfl_xor(sum, 32);
            const float inv = 1.0f / sum;
            #pragma unroll
            for (int i = 0; i < RT; ++i) {
                S[i][0] *= inv; S[i][1] *= inv; S[i][2] *= inv; S[i][3] *= inv;
            }

            float* arow = atn + ((long long)w * P + 16 * j + lo) * P + 4 * g;
            #pragma unroll
            for (int i = 0; i < RT; ++i)
                *reinterpret_cast<f32x4*>(arow + 16 * i) = S[i];

            f32x4 Y0 = {0.f, 0.f, 0.f, 0.f};
            f32x4 Y1 = {0.f, 0.f, 0.f, 0.f};
            #pragma unroll
            for (int i = 0; i < RT; ++i) {
                uint2 t2;
                t2.x = bfpack(S[i][0], S[i][1]);
                t2.y = bfpack(S[i][2], S[i][3]);
                bf16x4 pa = *reinterpret_cast<bf16x4*>(&t2);
                Y0 = mfma16(pa, VB[i][0], Y0);
                Y1 = mfma16(pa, VB[i][1], Y1);
            }

            unsigned short* ywp = ys + (wl * P + 16 * j + 4 * g) * 20;
            #pragma unroll
            for (int r = 0; r < 4; ++r) ywp[r * 20 + lo] = (unsigned short)bfrnd(Y0[r]);
            if (lo < 4) {
                #pragma unroll
                for (int r = 0; r < 4; ++r) ywp[r * 20 + 16 + lo] = (unsigned short)bfrnd(Y1[r]);
            }
        }
    }
    __syncthreads();

    for (int i = tid; i < NWIN * P * 5; i += BLOCK) {
        const int wl   = i / (P * 5);
        const int rem  = i - wl * (P * 5);
        const int pixr = rem / 5;
        const int c    = rem - pixr * 5;
        const int w2   = w0 + wl;
        const int b2   = w2 / (NWND * NWND);
        const int r2   = w2 - b2 * (NWND * NWND);
        const int wi2  = r2 / NWND;
        const int wj2  = r2 - wi2 * NWND;
        const int oh   = (wi2 * WS + pixr / WS + SH) % 288;
        const int ow   = (wj2 * WS + pixr % WS + SH) % 288;
        const uint2 v = *reinterpret_cast<const uint2*>(&ys[(wl * P + pixr) * 20 + c * 4]);
        *reinterpret_cast<uint2*>(ybuf + ((long long)(b2 * 3 + BRANCH) * HW + oh * 288 + ow) * 20 + c * 4) = v;
    }
}

// ---------------- proj_out ----------------
__global__ __launch_bounds__(256, 3) void proj_out_kernel(const unsigned short* __restrict__ ybuf,
                                                          const float* __restrict__ Wout,
                                                          const float* __restrict__ bout,
                                                          float* __restrict__ out) {
    __shared__ unsigned ystage[3][2560 + 8];
    __shared__ float ostage[15][260];
    const int tid = threadIdx.x;
    const long long pixel0 = (long long)blockIdx.x * 256;
    const int b   = (int)(pixel0 / HW);
    const int hw0 = (int)(pixel0 % HW);

    for (int i = tid; i < 3 * 640; i += 256) {
        const int br = i / 640, j = i - br * 640;
        const uint4 d = reinterpret_cast<const uint4*>(
            ybuf + ((long long)(b * 3 + br) * HW + hw0) * 20)[j];
        unsigned* dstl = &ystage[br][j * 4];
        dstl[0] = d.x; dstl[1] = d.y; dstl[2] = d.z; dstl[3] = d.w;
    }
    __syncthreads();

    float yv[60];
    #pragma unroll
    for (int br = 0; br < 3; ++br) {
        #pragma unroll
        for (int k = 0; k < 10; ++k) {
            const unsigned u = ystage[br][tid * 10 + k];
            yv[br * 20 + 2 * k]     = bflo(u);
            yv[br * 20 + 2 * k + 1] = bfhi(u);
        }
    }

    for (int c0 = 0; c0 < 60; c0 += 15) {
        #pragma unroll
        for (int oo = 0; oo < 15; ++oo) {
            const int o = c0 + oo;
            float acc = bout[o];
            const float* wr = Wout + o * 60;
            #pragma unroll
            for (int c = 0; c < 60; ++c) acc = fmaf(wr[c], yv[c], acc);
            ostage[oo][tid] = acc;
        }
        __syncthreads();
        for (int i = tid; i < 15 * 64; i += 256) {
            const int seg = i / 64, j = i - seg * 64;
            const float* sl = &ostage[seg][j * 4];
            float4 vq = make_float4(sl[0], sl[1], sl[2], sl[3]);
            *reinterpret_cast<float4*>(out + ((long long)b * 60 + c0 + seg) * HW + hw0 + j * 4) = vq;
        }
        __syncthreads();
    }
}

extern "C" void kernel_launch(void* const* d_in, const int* in_sizes, int n_in,
                              void* d_out, int out_size, void* d_ws, size_t ws_size,
                              hipStream_t stream) {
    const float* x     = (const float*)d_in[0];
    const float* W_in  = (const float*)d_in[1];
    const float* b_in  = (const float*)d_in[2];
    const float* gamma = (const float*)d_in[3];
    const float* beta  = (const float*)d_in[4];
    const float* mean  = (const float*)d_in[5];
    const float* var   = (const float*)d_in[6];
    const float* Wout  = (const float*)d_in[7];
    const float* bout  = (const float*)d_in[8];
    float* out = (float*)d_out;

    char* wsb = (char*)d_ws;
    unsigned short* ybuf = (unsigned short*)(wsb + YB_OFF);
    float*          Wp   = (float*)(wsb + WP_OFF);
    float*          bp   = (float*)(wsb + BP_OFF);
    unsigned short* xp   = (unsigned short*)(wsb + XP_OFF);

    prep_kernel<<<1, 128, 0, stream>>>(W_in, b_in, gamma, beta, mean, var, Wp, bp);
    proj_in_kernel<<<2592, 256, 0, stream>>>(x, Wp, bp, xp);

    branch_kernel<4, 16, 256, 1, 0, 4><<<2592, 256, 0, stream>>>(xp, ybuf, out + ATN0_OFF);
    branch_kernel<8,  4, 256, 1, 1, 3><<<2592, 256, 0, stream>>>(xp, ybuf, out + ATN1_OFF);
    branch_kernel<12, 2, 256, 2, 2, 2><<<2304, 256, 0, stream>>>(xp, ybuf, out + ATN2_OFF);

    proj_out_kernel<<<2592, 256, 0, stream>>>(ybuf, Wout, bout, out);
}

// Round 9
// 658.166 us; speedup vs baseline: 2.6083x; 1.0319x over previous
//
#include <hip/hip_runtime.h>

// GMSA R9 = R5 (last green, verbatim: prep / proj_in VALU / 3x MFMA branch kernels /
// workspace layout, total 159,281,792 B proven in-bounds) + ONE change:
// MFMA proj_out that stages W_out -> bf16 LDS per block (NO new workspace).
// d_out = [y (8,60,288,288), atn4, atn8, atn12] flat fp32.

constexpr int HW = 288 * 288;
constexpr long long ATN0_OFF = 39813120LL;
constexpr long long ATN1_OFF = ATN0_OFF + 41472LL * 256;
constexpr long long ATN2_OFF = ATN1_OFF + 10368LL * 4096;

// workspace layout: R5 EXACT (ends at 159,281,792 bytes)
constexpr size_t YB_OFF = 0;                        // ybuf: 39,813,120 ushort
constexpr size_t WP_OFF = 79626240;                 // Wp: 7200 float
constexpr size_t BP_OFF = WP_OFF + 28800;           // bp: 120 float (+pad)
constexpr size_t XP_OFF = BP_OFF + 512;             // xp: 39,813,120 ushort

typedef __attribute__((ext_vector_type(8))) short  bf16x8;
typedef __attribute__((ext_vector_type(4))) short  bf16x4;
typedef __attribute__((ext_vector_type(4))) float  f32x4;

__device__ __forceinline__ unsigned bfrnd(float f) {   // RNE to bf16 bits
    unsigned u = __float_as_uint(f);
    return (u + 0x7fffu + ((u >> 16) & 1u)) >> 16;
}
__device__ __forceinline__ unsigned bfpack(float a, float b) { return bfrnd(a) | (bfrnd(b) << 16); }

#if defined(__has_builtin)
#if __has_builtin(__builtin_amdgcn_mfma_f32_16x16x16bf16_1k)
#define HAVE_MFMA16 1
#endif
#endif

__device__ __forceinline__ f32x4 mfma16(bf16x4 a, bf16x4 b, f32x4 c) {
#ifdef HAVE_MFMA16
    return __builtin_amdgcn_mfma_f32_16x16x16bf16_1k(a, b, c, 0, 0, 0);
#else
    f32x4 d;
    asm("v_mfma_f32_16x16x16_bf16 %0, %1, %2, %3" : "=v"(d) : "v"(a), "v"(b), "v"(c));
    return d;
#endif
}

__device__ __forceinline__ f32x4 mfma32(bf16x8 a, bf16x8 b, f32x4 c) {
    return __builtin_amdgcn_mfma_f32_16x16x32_bf16(a, b, c, 0, 0, 0);
}

// ---------------- prep (R5 verbatim) ----------------
__global__ void prep_kernel(const float* __restrict__ W_in, const float* __restrict__ b_in,
                            const float* __restrict__ gamma, const float* __restrict__ beta,
                            const float* __restrict__ mean, const float* __restrict__ var,
                            float* __restrict__ Wp, float* __restrict__ bp) {
    int o = threadIdx.x;
    if (o < 120) {
        float inv = gamma[o] / sqrtf(var[o] + 1e-5f);
        for (int c = 0; c < 60; ++c) Wp[o * 60 + c] = W_in[o * 60 + c] * inv;
        bp[o] = b_in[o] * inv + beta[o] - mean[o] * inv;
    }
}

// ---------------- proj_in (R5 verbatim, VALU) ----------------
__global__ __launch_bounds__(256, 4) void proj_in_kernel(const float* __restrict__ x,
                                                         const float* __restrict__ Wp,
                                                         const float* __restrict__ bp,
                                                         unsigned short* __restrict__ xp) {
    __shared__ unsigned pk[256 * 21];
    const int tid = threadIdx.x;
    const long long pixel0 = (long long)blockIdx.x * 256;
    const int b   = (int)(pixel0 / HW);
    const int hw0 = (int)(pixel0 % HW);

    float xv[60];
    const float* xb = x + (long long)b * 60 * HW + hw0 + tid;
    #pragma unroll
    for (int c = 0; c < 60; ++c) xv[c] = xb[(long long)c * HW];

    for (int br = 0; br < 3; ++br) {
        #pragma unroll
        for (int g = 0; g < 5; ++g) {
            float a8[8];
            #pragma unroll
            for (int j = 0; j < 8; ++j) {
                const int oc = br * 40 + g * 8 + j;
                float acc = bp[oc];
                const float* wr = Wp + oc * 60;
                #pragma unroll
                for (int c = 0; c < 60; ++c) acc = fmaf(wr[c], xv[c], acc);
                a8[j] = acc;
            }
            pk[tid * 21 + g * 4 + 0] = bfpack(a8[0], a8[1]);
            pk[tid * 21 + g * 4 + 1] = bfpack(a8[2], a8[3]);
            pk[tid * 21 + g * 4 + 2] = bfpack(a8[4], a8[5]);
            pk[tid * 21 + g * 4 + 3] = bfpack(a8[6], a8[7]);
        }
        __syncthreads();
        uint4* dst = reinterpret_cast<uint4*>(xp + ((long long)(b * 3 + br) * HW + hw0) * 40);
        #pragma unroll
        for (int it = 0; it < 5; ++it) {
            const int i = it * 256 + tid;
            const int p = i / 5, c = i % 5;
            const unsigned* s = pk + p * 21 + c * 4;
            dst[i] = make_uint4(s[0], s[1], s[2], s[3]);
        }
        __syncthreads();
    }
}

// ---------------- MFMA branch attention (R5 verbatim) ----------------
template <int WS, int NWIN, int BLOCK, int WPW, int BRANCH, int MINW>
__launch_bounds__(BLOCK, MINW)
__global__ void branch_kernel(const unsigned short* __restrict__ xp,
                              unsigned short* __restrict__ ybuf,
                              float* __restrict__ atn) {
    constexpr int P    = WS * WS;
    constexpr int RT   = P / 16;
    constexpr int SH   = WS / 2;
    constexpr int NWND = 288 / WS;
    constexpr int RSTR = 56;
    constexpr int WAVES = BLOCK / 64;
    constexpr int WINS_PER_WAVE = (NWIN * WPW) / WAVES;

    __shared__ __align__(16) unsigned short qv[NWIN * P * RSTR];
    __shared__ __align__(16) unsigned short ys[NWIN * P * 20];

    const int tid = threadIdx.x;
    const int w0 = blockIdx.x * NWIN;

    for (int idx = tid; idx < NWIN * P * 5; idx += BLOCK) {
        const int wl  = idx / (P * 5);
        const int rem = idx - wl * (P * 5);
        const int pix = rem / 5;
        const int ck  = rem - pix * 5;
        const int w   = w0 + wl;
        const int b   = w / (NWND * NWND);
        const int r2  = w - b * (NWND * NWND);
        const int wi  = r2 / NWND;
        const int wj  = r2 - wi * NWND;
        const int gh  = (wi * WS + pix / WS + SH) % 288;
        const int gw  = (wj * WS + pix % WS + SH) % 288;
        const uint4 d = *reinterpret_cast<const uint4*>(
            xp + ((long long)(b * 3 + BRANCH) * HW + gh * 288 + gw) * 40 + ck * 8);
        *reinterpret_cast<uint4*>(&qv[(wl * P + pix) * RSTR + ck * 8]) = d;
    }
    __syncthreads();

    const int wave = tid >> 6;
    const int lane = tid & 63;
    const int lo   = lane & 15;
    const int g    = lane >> 4;

    for (int wk = 0; wk < WINS_PER_WAVE; ++wk) {
        const int wl   = (WPW == 1) ? (wave * WINS_PER_WAVE + wk) : (wave >> 1);
        const int half = (WPW == 1) ? 0 : (wave & 1);
        const int w    = w0 + wl;
        const unsigned short* wbase = qv + wl * P * RSTR;

        bf16x8 F[RT];
        #pragma unroll
        for (int t = 0; t < RT; ++t) {
            uint4 u = *reinterpret_cast<const uint4*>(&wbase[(16 * t + lo) * RSTR + g * 8]);
            if (g == 2) { u.z = 0; u.w = 0; }
            if (g == 3) { u.x = 0; u.y = 0; u.z = 0; u.w = 0; }
            F[t] = *reinterpret_cast<bf16x8*>(&u);
        }

        bf16x4 VB[RT][2];
        #pragma unroll
        for (int i = 0; i < RT; ++i) {
            #pragma unroll
            for (int ct = 0; ct < 2; ++ct) {
                const int c = ct * 16 + lo;
                bf16x4 vv;
                #pragma unroll
                for (int jj = 0; jj < 4; ++jj) {
                    const int row = 16 * i + 4 * g + jj;
                    vv[jj] = (c < 20) ? (short)wbase[row * RSTR + 20 + c] : (short)0;
                }
                VB[i][ct] = vv;
            }
        }

        const int jstart = (WPW == 1) ? 0 : (half * ((RT + 1) / 2));
        const int jend   = (WPW == 1) ? RT : ((half == 0) ? ((RT + 1) / 2) : RT);
        for (int j = jstart; j < jend; ++j) {
            f32x4 S[RT];
            #pragma unroll
            for (int i = 0; i < RT; ++i) {
                f32x4 z = {0.f, 0.f, 0.f, 0.f};
                S[i] = mfma32(F[i], F[j], z);
            }

            float m = S[0][0];
            #pragma unroll
            for (int i = 0; i < RT; ++i) {
                #pragma unroll
                for (int r = 0; r < 4; ++r) m = fmaxf(m, S[i][r]);
            }
            m = fmaxf(m, __shfl_xor(m, 16));
            m = fmaxf(m, __shfl_xor(m, 32));
            float sum = 0.f;
            #pragma unroll
            for (int i = 0; i < RT; ++i) {
                #pragma unroll
                for (int r = 0; r < 4; ++r) { float e = __expf(S[i][r] - m); S[i][r] = e; sum += e; }
            }
            sum += __shfl_xor(sum, 16);
            sum += __shfl_xor(sum, 32);
            const float inv = 1.0f / sum;
            #pragma unroll
            for (int i = 0; i < RT; ++i) {
                S[i][0] *= inv; S[i][1] *= inv; S[i][2] *= inv; S[i][3] *= inv;
            }

            float* arow = atn + ((long long)w * P + 16 * j + lo) * P + 4 * g;
            #pragma unroll
            for (int i = 0; i < RT; ++i)
                *reinterpret_cast<f32x4*>(arow + 16 * i) = S[i];

            f32x4 Y0 = {0.f, 0.f, 0.f, 0.f};
            f32x4 Y1 = {0.f, 0.f, 0.f, 0.f};
            #pragma unroll
            for (int i = 0; i < RT; ++i) {
                uint2 t2;
                t2.x = bfpack(S[i][0], S[i][1]);
                t2.y = bfpack(S[i][2], S[i][3]);
                bf16x4 pa = *reinterpret_cast<bf16x4*>(&t2);
                Y0 = mfma16(pa, VB[i][0], Y0);
                Y1 = mfma16(pa, VB[i][1], Y1);
            }

            unsigned short* ywp = ys + (wl * P + 16 * j + 4 * g) * 20;
            #pragma unroll
            for (int r = 0; r < 4; ++r) ywp[r * 20 + lo] = (unsigned short)bfrnd(Y0[r]);
            if (lo < 4) {
                #pragma unroll
                for (int r = 0; r < 4; ++r) ywp[r * 20 + 16 + lo] = (unsigned short)bfrnd(Y1[r]);
            }
        }
    }
    __syncthreads();

    for (int i = tid; i < NWIN * P * 5; i += BLOCK) {
        const int wl   = i / (P * 5);
        const int rem  = i - wl * (P * 5);
        const int pixr = rem / 5;
        const int c    = rem - pixr * 5;
        const int w2   = w0 + wl;
        const int b2   = w2 / (NWND * NWND);
        const int r2   = w2 - b2 * (NWND * NWND);
        const int wi2  = r2 / NWND;
        const int wj2  = r2 - wi2 * NWND;
        const int oh   = (wi2 * WS + pixr / WS + SH) % 288;
        const int ow   = (wj2 * WS + pixr % WS + SH) % 288;
        const uint2 v = *reinterpret_cast<const uint2*>(&ys[(wl * P + pixr) * 20 + c * 4]);
        *reinterpret_cast<uint2*>(ybuf + ((long long)(b2 * 3 + BRANCH) * HW + oh * 288 + ow) * 20 + c * 4) = v;
    }
}

// ---------------- proj_out: MFMA, 128 px/block, W_out staged to LDS (no workspace) ----------------
__global__ __launch_bounds__(256, 2) void proj_out_kernel(const unsigned short* __restrict__ ybuf,
                                                          const float* __restrict__ W_out,
                                                          const float* __restrict__ bout,
                                                          float* __restrict__ out) {
    __shared__ __align__(16) unsigned short yh[128 * 72];   // [pixel][ch 0..63, 64..71 pad]
    __shared__ __align__(16) unsigned short wq[64 * 64];    // [oc][ch] bf16, zero-padded
    __shared__ __align__(16) float ost[60 * 132];           // [oc][pixel pad]

    const int tid = threadIdx.x;
    const long long pixel0 = (long long)blockIdx.x * 128;
    const int b   = (int)(pixel0 / HW);
    const int hw0 = (int)(pixel0 % HW);

    // stage W_out (fp32 global, L2-resident) -> bf16 LDS tile
    for (int i = tid; i < 4096; i += 256) {
        const int row = i >> 6, ch = i & 63;
        wq[i] = (row < 60 && ch < 60) ? (unsigned short)bfrnd(W_out[row * 60 + ch]) : (unsigned short)0;
    }

    // stage ybuf (bf16) -> yh[pixel][ch 0..59], zero 60..67
    for (int i = tid; i < 1920; i += 256) {
        const int br = i / 640, j = i - br * 640, p = j / 5, c = j - p * 5;
        const uint2 v = reinterpret_cast<const uint2*>(
            ybuf + ((long long)(b * 3 + br) * HW + hw0) * 20)[j];
        *reinterpret_cast<uint2*>(&yh[p * 72 + br * 20 + c * 4]) = v;
    }
    {
        const int p = tid >> 1, hh = tid & 1;
        *reinterpret_cast<uint2*>(&yh[p * 72 + 60 + hh * 4]) = make_uint2(0, 0);
    }
    __syncthreads();

    const int wave = tid >> 6, lane = tid & 63, lo = lane & 15, g = lane >> 4;

    uint4 alo[2], ahi[2];
    #pragma unroll
    for (int mt2 = 0; mt2 < 2; ++mt2) {
        const int row = (wave * 2 + mt2) * 16 + lo;
        alo[mt2] = *reinterpret_cast<const uint4*>(&yh[row * 72 + g * 8]);
        ahi[mt2] = *reinterpret_cast<const uint4*>(&yh[row * 72 + 32 + g * 8]);
    }

    #pragma unroll
    for (int n = 0; n < 4; ++n) {
        uint4 wfl = *reinterpret_cast<const uint4*>(&wq[(n * 16 + lo) * 64 + g * 8]);
        uint4 wfh = *reinterpret_cast<const uint4*>(&wq[(n * 16 + lo) * 64 + 32 + g * 8]);
        const int oc = n * 16 + lo;
        const float bo = (oc < 60) ? bout[oc] : 0.f;
        #pragma unroll
        for (int mt2 = 0; mt2 < 2; ++mt2) {
            f32x4 z = {0.f, 0.f, 0.f, 0.f};
            f32x4 acc = mfma32(*reinterpret_cast<bf16x8*>(&alo[mt2]),
                               *reinterpret_cast<bf16x8*>(&wfl), z);
            acc = mfma32(*reinterpret_cast<bf16x8*>(&ahi[mt2]),
                         *reinterpret_cast<bf16x8*>(&wfh), acc);
            if (oc < 60) {
                const int pcol = (wave * 2 + mt2) * 16 + 4 * g;
                #pragma unroll
                for (int r = 0; r < 4; ++r)
                    ost[oc * 132 + pcol + r] = acc[r] + bo;
            }
        }
    }
    __syncthreads();

    // dense channel-major store: 60 channels * 512B segments
    for (int i = tid; i < 1920; i += 256) {
        const int o = i >> 5, j = i & 31;
        const f32x4 v = *reinterpret_cast<const f32x4*>(&ost[o * 132 + j * 4]);
        *reinterpret_cast<f32x4*>(&out[((long long)b * 60 + o) * HW + hw0 + j * 4]) = v;
    }
}

extern "C" void kernel_launch(void* const* d_in, const int* in_sizes, int n_in,
                              void* d_out, int out_size, void* d_ws, size_t ws_size,
                              hipStream_t stream) {
    const float* x     = (const float*)d_in[0];
    const float* W_in  = (const float*)d_in[1];
    const float* b_in  = (const float*)d_in[2];
    const float* gamma = (const float*)d_in[3];
    const float* beta  = (const float*)d_in[4];
    const float* mean  = (const float*)d_in[5];
    const float* var   = (const float*)d_in[6];
    const float* Wout  = (const float*)d_in[7];
    const float* bout  = (const float*)d_in[8];
    float* out = (float*)d_out;

    char* wsb = (char*)d_ws;
    unsigned short* ybuf = (unsigned short*)(wsb + YB_OFF);
    float*          Wp   = (float*)(wsb + WP_OFF);
    float*          bp   = (float*)(wsb + BP_OFF);
    unsigned short* xp   = (unsigned short*)(wsb + XP_OFF);

    prep_kernel<<<1, 128, 0, stream>>>(W_in, b_in, gamma, beta, mean, var, Wp, bp);
    proj_in_kernel<<<2592, 256, 0, stream>>>(x, Wp, bp, xp);

    branch_kernel<4, 16, 256, 1, 0, 4><<<2592, 256, 0, stream>>>(xp, ybuf, out + ATN0_OFF);
    branch_kernel<8,  4, 256, 1, 1, 3><<<2592, 256, 0, stream>>>(xp, ybuf, out + ATN1_OFF);
    branch_kernel<12, 2, 256, 2, 2, 2><<<2304, 256, 0, stream>>>(xp, ybuf, out + ATN2_OFF);

    proj_out_kernel<<<5184, 256, 0, stream>>>(ybuf, Wout, bout, out);
}

// Round 10
// 508.283 us; speedup vs baseline: 3.3774x; 1.2949x over previous
//
#include <hip/hip_runtime.h>

// GMSA R10 = R9 (green: prep / MFMA branches / MFMA proj_out, workspace 159,281,792 B)
// + ONE change: MFMA proj_in (Wp staged fp32->bf16 LDS per block; A-frags loaded
// directly from global x with in-register bf16 conversion; NO new workspace).
// d_out = [y (8,60,288,288), atn4, atn8, atn12] flat fp32.

constexpr int HW = 288 * 288;
constexpr long long ATN0_OFF = 39813120LL;
constexpr long long ATN1_OFF = ATN0_OFF + 41472LL * 256;
constexpr long long ATN2_OFF = ATN1_OFF + 10368LL * 4096;

// workspace layout: R5/R9 EXACT (ends at 159,281,792 bytes)
constexpr size_t YB_OFF = 0;                        // ybuf: 39,813,120 ushort
constexpr size_t WP_OFF = 79626240;                 // Wp: 7200 float
constexpr size_t BP_OFF = WP_OFF + 28800;           // bp: 120 float (+pad)
constexpr size_t XP_OFF = BP_OFF + 512;             // xp: 39,813,120 ushort

typedef __attribute__((ext_vector_type(8))) short  bf16x8;
typedef __attribute__((ext_vector_type(4))) short  bf16x4;
typedef __attribute__((ext_vector_type(4))) float  f32x4;

__device__ __forceinline__ unsigned bfrnd(float f) {   // RNE to bf16 bits
    unsigned u = __float_as_uint(f);
    return (u + 0x7fffu + ((u >> 16) & 1u)) >> 16;
}
__device__ __forceinline__ unsigned bfpack(float a, float b) { return bfrnd(a) | (bfrnd(b) << 16); }

#if defined(__has_builtin)
#if __has_builtin(__builtin_amdgcn_mfma_f32_16x16x16bf16_1k)
#define HAVE_MFMA16 1
#endif
#endif

__device__ __forceinline__ f32x4 mfma16(bf16x4 a, bf16x4 b, f32x4 c) {
#ifdef HAVE_MFMA16
    return __builtin_amdgcn_mfma_f32_16x16x16bf16_1k(a, b, c, 0, 0, 0);
#else
    f32x4 d;
    asm("v_mfma_f32_16x16x16_bf16 %0, %1, %2, %3" : "=v"(d) : "v"(a), "v"(b), "v"(c));
    return d;
#endif
}

__device__ __forceinline__ f32x4 mfma32(bf16x8 a, bf16x8 b, f32x4 c) {
    return __builtin_amdgcn_mfma_f32_16x16x32_bf16(a, b, c, 0, 0, 0);
}

// ---------------- prep (R5 verbatim) ----------------
__global__ void prep_kernel(const float* __restrict__ W_in, const float* __restrict__ b_in,
                            const float* __restrict__ gamma, const float* __restrict__ beta,
                            const float* __restrict__ mean, const float* __restrict__ var,
                            float* __restrict__ Wp, float* __restrict__ bp) {
    int o = threadIdx.x;
    if (o < 120) {
        float inv = gamma[o] / sqrtf(var[o] + 1e-5f);
        for (int c = 0; c < 60; ++c) Wp[o * 60 + c] = W_in[o * 60 + c] * inv;
        bp[o] = b_in[o] * inv + beta[o] - mean[o] * inv;
    }
}

// ---------------- proj_in: MFMA, 128 px/block (the ONE new piece) ----------------
__global__ __launch_bounds__(256, 3) void proj_in_kernel(const float* __restrict__ x,
                                                         const float* __restrict__ Wp,
                                                         const float* __restrict__ bp,
                                                         unsigned short* __restrict__ xp) {
    __shared__ __align__(16) unsigned short wq[128 * 64];   // [oc 0..119 pad][ch 0..63] bf16
    __shared__ __align__(16) unsigned short ys[128 * 120];  // [pixel][oc]

    const int tid = threadIdx.x;
    const long long pixel0 = (long long)blockIdx.x * 128;   // HW % 128 == 0
    const int b   = (int)(pixel0 / HW);
    const int hw0 = (int)(pixel0 % HW);

    // stage Wp (fp32, L2-resident) -> bf16 LDS tile
    for (int i = tid; i < 8192; i += 256) {
        const int row = i >> 6, ch = i & 63;
        wq[i] = (row < 120 && ch < 60) ? (unsigned short)bfrnd(Wp[row * 60 + ch]) : (unsigned short)0;
    }

    const int wave = tid >> 6, lane = tid & 63, lo = lane & 15, g = lane >> 4;

    // A-frags direct from global x (16 consecutive pixels per 64B segment)
    uint4 alo[2], ahi[2];
    #pragma unroll
    for (int mt2 = 0; mt2 < 2; ++mt2) {
        const int row = (wave * 2 + mt2) * 16 + lo;          // pixel in block
        const float* xb = x + (long long)b * 60 * HW + hw0 + row;
        unsigned short tl[8], th[8];
        #pragma unroll
        for (int e = 0; e < 8; ++e) {
            const int cl = g * 8 + e;                        // 0..31, always < 60
            tl[e] = (unsigned short)bfrnd(xb[(long long)cl * HW]);
            const int ch = 32 + g * 8 + e;                   // 32..63
            th[e] = (ch < 60) ? (unsigned short)bfrnd(xb[(long long)ch * HW]) : (unsigned short)0;
        }
        alo[mt2] = *reinterpret_cast<const uint4*>(tl);
        ahi[mt2] = *reinterpret_cast<const uint4*>(th);
    }
    __syncthreads();   // wq ready

    #pragma unroll
    for (int n = 0; n < 8; ++n) {
        uint4 wfl = *reinterpret_cast<const uint4*>(&wq[(n * 16 + lo) * 64 + g * 8]);
        uint4 wfh = *reinterpret_cast<const uint4*>(&wq[(n * 16 + lo) * 64 + 32 + g * 8]);
        const int oc = n * 16 + lo;
        const float bb = bp[oc & 127];
        #pragma unroll
        for (int mt2 = 0; mt2 < 2; ++mt2) {
            f32x4 z = {0.f, 0.f, 0.f, 0.f};
            f32x4 acc = mfma32(*reinterpret_cast<bf16x8*>(&alo[mt2]),
                               *reinterpret_cast<bf16x8*>(&wfl), z);
            acc = mfma32(*reinterpret_cast<bf16x8*>(&ahi[mt2]),
                         *reinterpret_cast<bf16x8*>(&wfh), acc);
            if (oc < 120) {
                const int prow = (wave * 2 + mt2) * 16 + 4 * g;
                #pragma unroll
                for (int r = 0; r < 4; ++r)
                    ys[(prow + r) * 120 + oc] = (unsigned short)bfrnd(acc[r] + bb);
            }
        }
    }
    __syncthreads();

    // dense burst: per branch 128 pixels * 10 uint2 contiguous
    for (int i = tid; i < 3 * 1280; i += 256) {
        const int br = i / 1280, j = i - br * 1280, p = j / 10, c = j - p * 10;
        const uint2 v = *reinterpret_cast<const uint2*>(&ys[p * 120 + br * 40 + c * 4]);
        reinterpret_cast<uint2*>(xp + ((long long)(b * 3 + br) * HW + hw0) * 40)[p * 10 + c] = v;
    }
}

// ---------------- MFMA branch attention (R5/R9 verbatim) ----------------
template <int WS, int NWIN, int BLOCK, int WPW, int BRANCH, int MINW>
__launch_bounds__(BLOCK, MINW)
__global__ void branch_kernel(const unsigned short* __restrict__ xp,
                              unsigned short* __restrict__ ybuf,
                              float* __restrict__ atn) {
    constexpr int P    = WS * WS;
    constexpr int RT   = P / 16;
    constexpr int SH   = WS / 2;
    constexpr int NWND = 288 / WS;
    constexpr int RSTR = 56;
    constexpr int WAVES = BLOCK / 64;
    constexpr int WINS_PER_WAVE = (NWIN * WPW) / WAVES;

    __shared__ __align__(16) unsigned short qv[NWIN * P * RSTR];
    __shared__ __align__(16) unsigned short ys[NWIN * P * 20];

    const int tid = threadIdx.x;
    const int w0 = blockIdx.x * NWIN;

    for (int idx = tid; idx < NWIN * P * 5; idx += BLOCK) {
        const int wl  = idx / (P * 5);
        const int rem = idx - wl * (P * 5);
        const int pix = rem / 5;
        const int ck  = rem - pix * 5;
        const int w   = w0 + wl;
        const int b   = w / (NWND * NWND);
        const int r2  = w - b * (NWND * NWND);
        const int wi  = r2 / NWND;
        const int wj  = r2 - wi * NWND;
        const int gh  = (wi * WS + pix / WS + SH) % 288;
        const int gw  = (wj * WS + pix % WS + SH) % 288;
        const uint4 d = *reinterpret_cast<const uint4*>(
            xp + ((long long)(b * 3 + BRANCH) * HW + gh * 288 + gw) * 40 + ck * 8);
        *reinterpret_cast<uint4*>(&qv[(wl * P + pix) * RSTR + ck * 8]) = d;
    }
    __syncthreads();

    const int wave = tid >> 6;
    const int lane = tid & 63;
    const int lo   = lane & 15;
    const int g    = lane >> 4;

    for (int wk = 0; wk < WINS_PER_WAVE; ++wk) {
        const int wl   = (WPW == 1) ? (wave * WINS_PER_WAVE + wk) : (wave >> 1);
        const int half = (WPW == 1) ? 0 : (wave & 1);
        const int w    = w0 + wl;
        const unsigned short* wbase = qv + wl * P * RSTR;

        bf16x8 F[RT];
        #pragma unroll
        for (int t = 0; t < RT; ++t) {
            uint4 u = *reinterpret_cast<const uint4*>(&wbase[(16 * t + lo) * RSTR + g * 8]);
            if (g == 2) { u.z = 0; u.w = 0; }
            if (g == 3) { u.x = 0; u.y = 0; u.z = 0; u.w = 0; }
            F[t] = *reinterpret_cast<bf16x8*>(&u);
        }

        bf16x4 VB[RT][2];
        #pragma unroll
        for (int i = 0; i < RT; ++i) {
            #pragma unroll
            for (int ct = 0; ct < 2; ++ct) {
                const int c = ct * 16 + lo;
                bf16x4 vv;
                #pragma unroll
                for (int jj = 0; jj < 4; ++jj) {
                    const int row = 16 * i + 4 * g + jj;
                    vv[jj] = (c < 20) ? (short)wbase[row * RSTR + 20 + c] : (short)0;
                }
                VB[i][ct] = vv;
            }
        }

        const int jstart = (WPW == 1) ? 0 : (half * ((RT + 1) / 2));
        const int jend   = (WPW == 1) ? RT : ((half == 0) ? ((RT + 1) / 2) : RT);
        for (int j = jstart; j < jend; ++j) {
            f32x4 S[RT];
            #pragma unroll
            for (int i = 0; i < RT; ++i) {
                f32x4 z = {0.f, 0.f, 0.f, 0.f};
                S[i] = mfma32(F[i], F[j], z);
            }

            float m = S[0][0];
            #pragma unroll
            for (int i = 0; i < RT; ++i) {
                #pragma unroll
                for (int r = 0; r < 4; ++r) m = fmaxf(m, S[i][r]);
            }
            m = fmaxf(m, __shfl_xor(m, 16));
            m = fmaxf(m, __shfl_xor(m, 32));
            float sum = 0.f;
            #pragma unroll
            for (int i = 0; i < RT; ++i) {
                #pragma unroll
                for (int r = 0; r < 4; ++r) { float e = __expf(S[i][r] - m); S[i][r] = e; sum += e; }
            }
            sum += __shfl_xor(sum, 16);
            sum += __shfl_xor(sum, 32);
            const float inv = 1.0f / sum;
            #pragma unroll
            for (int i = 0; i < RT; ++i) {
                S[i][0] *= inv; S[i][1] *= inv; S[i][2] *= inv; S[i][3] *= inv;
            }

            float* arow = atn + ((long long)w * P + 16 * j + lo) * P + 4 * g;
            #pragma unroll
            for (int i = 0; i < RT; ++i)
                *reinterpret_cast<f32x4*>(arow + 16 * i) = S[i];

            f32x4 Y0 = {0.f, 0.f, 0.f, 0.f};
            f32x4 Y1 = {0.f, 0.f, 0.f, 0.f};
            #pragma unroll
            for (int i = 0; i < RT; ++i) {
                uint2 t2;
                t2.x = bfpack(S[i][0], S[i][1]);
                t2.y = bfpack(S[i][2], S[i][3]);
                bf16x4 pa = *reinterpret_cast<bf16x4*>(&t2);
                Y0 = mfma16(pa, VB[i][0], Y0);
                Y1 = mfma16(pa, VB[i][1], Y1);
            }

            unsigned short* ywp = ys + (wl * P + 16 * j + 4 * g) * 20;
            #pragma unroll
            for (int r = 0; r < 4; ++r) ywp[r * 20 + lo] = (unsigned short)bfrnd(Y0[r]);
            if (lo < 4) {
                #pragma unroll
                for (int r = 0; r < 4; ++r) ywp[r * 20 + 16 + lo] = (unsigned short)bfrnd(Y1[r]);
            }
        }
    }
    __syncthreads();

    for (int i = tid; i < NWIN * P * 5; i += BLOCK) {
        const int wl   = i / (P * 5);
        const int rem  = i - wl * (P * 5);
        const int pixr = rem / 5;
        const int c    = rem - pixr * 5;
        const int w2   = w0 + wl;
        const int b2   = w2 / (NWND * NWND);
        const int r2   = w2 - b2 * (NWND * NWND);
        const int wi2  = r2 / NWND;
        const int wj2  = r2 - wi2 * NWND;
        const int oh   = (wi2 * WS + pixr / WS + SH) % 288;
        const int ow   = (wj2 * WS + pixr % WS + SH) % 288;
        const uint2 v = *reinterpret_cast<const uint2*>(&ys[(wl * P + pixr) * 20 + c * 4]);
        *reinterpret_cast<uint2*>(ybuf + ((long long)(b2 * 3 + BRANCH) * HW + oh * 288 + ow) * 20 + c * 4) = v;
    }
}

// ---------------- proj_out (R9 verbatim: MFMA, W_out staged to LDS) ----------------
__global__ __launch_bounds__(256, 2) void proj_out_kernel(const unsigned short* __restrict__ ybuf,
                                                          const float* __restrict__ W_out,
                                                          const float* __restrict__ bout,
                                                          float* __restrict__ out) {
    __shared__ __align__(16) unsigned short yh[128 * 72];   // [pixel][ch 0..63, 64..71 pad]
    __shared__ __align__(16) unsigned short wq[64 * 64];    // [oc][ch] bf16, zero-padded
    __shared__ __align__(16) float ost[60 * 132];           // [oc][pixel pad]

    const int tid = threadIdx.x;
    const long long pixel0 = (long long)blockIdx.x * 128;
    const int b   = (int)(pixel0 / HW);
    const int hw0 = (int)(pixel0 % HW);

    for (int i = tid; i < 4096; i += 256) {
        const int row = i >> 6, ch = i & 63;
        wq[i] = (row < 60 && ch < 60) ? (unsigned short)bfrnd(W_out[row * 60 + ch]) : (unsigned short)0;
    }

    for (int i = tid; i < 1920; i += 256) {
        const int br = i / 640, j = i - br * 640, p = j / 5, c = j - p * 5;
        const uint2 v = reinterpret_cast<const uint2*>(
            ybuf + ((long long)(b * 3 + br) * HW + hw0) * 20)[j];
        *reinterpret_cast<uint2*>(&yh[p * 72 + br * 20 + c * 4]) = v;
    }
    {
        const int p = tid >> 1, hh = tid & 1;
        *reinterpret_cast<uint2*>(&yh[p * 72 + 60 + hh * 4]) = make_uint2(0, 0);
    }
    __syncthreads();

    const int wave = tid >> 6, lane = tid & 63, lo = lane & 15, g = lane >> 4;

    uint4 alo[2], ahi[2];
    #pragma unroll
    for (int mt2 = 0; mt2 < 2; ++mt2) {
        const int row = (wave * 2 + mt2) * 16 + lo;
        alo[mt2] = *reinterpret_cast<const uint4*>(&yh[row * 72 + g * 8]);
        ahi[mt2] = *reinterpret_cast<const uint4*>(&yh[row * 72 + 32 + g * 8]);
    }

    #pragma unroll
    for (int n = 0; n < 4; ++n) {
        uint4 wfl = *reinterpret_cast<const uint4*>(&wq[(n * 16 + lo) * 64 + g * 8]);
        uint4 wfh = *reinterpret_cast<const uint4*>(&wq[(n * 16 + lo) * 64 + 32 + g * 8]);
        const int oc = n * 16 + lo;
        const float bo = (oc < 60) ? bout[oc] : 0.f;
        #pragma unroll
        for (int mt2 = 0; mt2 < 2; ++mt2) {
            f32x4 z = {0.f, 0.f, 0.f, 0.f};
            f32x4 acc = mfma32(*reinterpret_cast<bf16x8*>(&alo[mt2]),
                               *reinterpret_cast<bf16x8*>(&wfl), z);
            acc = mfma32(*reinterpret_cast<bf16x8*>(&ahi[mt2]),
                         *reinterpret_cast<bf16x8*>(&wfh), acc);
            if (oc < 60) {
                const int pcol = (wave * 2 + mt2) * 16 + 4 * g;
                #pragma unroll
                for (int r = 0; r < 4; ++r)
                    ost[oc * 132 + pcol + r] = acc[r] + bo;
            }
        }
    }
    __syncthreads();

    for (int i = tid; i < 1920; i += 256) {
        const int o = i >> 5, j = i & 31;
        const f32x4 v = *reinterpret_cast<const f32x4*>(&ost[o * 132 + j * 4]);
        *reinterpret_cast<f32x4*>(&out[((long long)b * 60 + o) * HW + hw0 + j * 4]) = v;
    }
}

extern "C" void kernel_launch(void* const* d_in, const int* in_sizes, int n_in,
                              void* d_out, int out_size, void* d_ws, size_t ws_size,
                              hipStream_t stream) {
    const float* x     = (const float*)d_in[0];
    const float* W_in  = (const float*)d_in[1];
    const float* b_in  = (const float*)d_in[2];
    const float* gamma = (const float*)d_in[3];
    const float* beta  = (const float*)d_in[4];
    const float* mean  = (const float*)d_in[5];
    const float* var   = (const float*)d_in[6];
    const float* Wout  = (const float*)d_in[7];
    const float* bout  = (const float*)d_in[8];
    float* out = (float*)d_out;

    char* wsb = (char*)d_ws;
    unsigned short* ybuf = (unsigned short*)(wsb + YB_OFF);
    float*          Wp   = (float*)(wsb + WP_OFF);
    float*          bp   = (float*)(wsb + BP_OFF);
    unsigned short* xp   = (unsigned short*)(wsb + XP_OFF);

    prep_kernel<<<1, 128, 0, stream>>>(W_in, b_in, gamma, beta, mean, var, Wp, bp);
    proj_in_kernel<<<5184, 256, 0, stream>>>(x, Wp, bp, xp);

    branch_kernel<4, 16, 256, 1, 0, 4><<<2592, 256, 0, stream>>>(xp, ybuf, out + ATN0_OFF);
    branch_kernel<8,  4, 256, 1, 1, 3><<<2592, 256, 0, stream>>>(xp, ybuf, out + ATN1_OFF);
    branch_kernel<12, 2, 256, 2, 2, 2><<<2304, 256, 0, stream>>>(xp, ybuf, out + ATN2_OFF);

    proj_out_kernel<<<5184, 256, 0, stream>>>(ybuf, Wout, bout, out);
}